// Round 1
// baseline (374.561 us; speedup 1.0000x reference)
//
#include <hip/hip_runtime.h>
#include <math.h>

#define BATCH 32
#define NROWS 4096
#define CDIM  512
#define EPS_INV 10.0f   // 1/EPS_SINKHORN

// ---------------------------------------------------------------------------
// Pass 1: fused l2norm + similarity + exp-weight + weighted accumulation.
// Grid: (chunks, BATCH), block = 256 threads = 4 waves.
// Each wave processes rows_per_wave rows; lane i owns columns
// {4i..4i+3} and {256+4i..256+4i+3} (two coalesced float4 loads per row).
// Per-block partial acc[512] and partial sum-of-weights go to workspace.
// ---------------------------------------------------------------------------
__global__ __launch_bounds__(256) void uot_pass1(
    const float* __restrict__ prompt,     // [BATCH, CDIM]
    const float* __restrict__ vf,         // [BATCH, NROWS, CDIM]
    float* __restrict__ ws_acc,           // [BATCH*chunks, CDIM]
    float* __restrict__ ws_l,             // [BATCH*chunks]
    int chunks)
{
    const int b     = blockIdx.y;
    const int chunk = blockIdx.x;
    const int lane  = threadIdx.x & 63;
    const int wave  = threadIdx.x >> 6;

    // ---- normalized prompt fragment (redundant per wave, tiny) ----
    const float* pp = prompt + (size_t)b * CDIM;
    float4 pa = *(const float4*)(pp + 4 * lane);
    float4 pb = *(const float4*)(pp + (CDIM / 2) + 4 * lane);
    float ss = pa.x*pa.x + pa.y*pa.y + pa.z*pa.z + pa.w*pa.w
             + pb.x*pb.x + pb.y*pb.y + pb.z*pb.z + pb.w*pb.w;
    #pragma unroll
    for (int off = 32; off > 0; off >>= 1) ss += __shfl_xor(ss, off);
    const float pinv = 1.0f / fmaxf(sqrtf(ss), 1e-12f);
    pa.x *= pinv; pa.y *= pinv; pa.z *= pinv; pa.w *= pinv;
    pb.x *= pinv; pb.y *= pinv; pb.z *= pinv; pb.w *= pinv;

    float4 acc_a = make_float4(0.f, 0.f, 0.f, 0.f);
    float4 acc_b = make_float4(0.f, 0.f, 0.f, 0.f);
    float  lsum  = 0.f;

    const int rows_per_chunk = NROWS / chunks;
    const int rows_per_wave  = rows_per_chunk >> 2;
    const int row0 = chunk * rows_per_chunk + wave * rows_per_wave;
    const float* __restrict__ base = vf + ((size_t)b * NROWS + row0) * CDIM;

    #pragma unroll 2
    for (int r = 0; r < rows_per_wave; ++r) {
        const float* __restrict__ vrow = base + (size_t)r * CDIM;
        const float4 va = *(const float4*)(vrow + 4 * lane);
        const float4 vb = *(const float4*)(vrow + (CDIM / 2) + 4 * lane);

        float s = va.x*pa.x + va.y*pa.y + va.z*pa.z + va.w*pa.w
                + vb.x*pb.x + vb.y*pb.y + vb.z*pb.z + vb.w*pb.w;
        float q = va.x*va.x + va.y*va.y + va.z*va.z + va.w*va.w
                + vb.x*vb.x + vb.y*vb.y + vb.z*vb.z + vb.w*vb.w;

        #pragma unroll
        for (int off = 32; off > 0; off >>= 1) {
            s += __shfl_xor(s, off);
            q += __shfl_xor(q, off);
        }

        // inv = 1/max(||v||, 1e-12); ||v|| ~ 22 for these inputs, guard via q
        const float inv = rsqrtf(fmaxf(q, 1e-24f));
        const float sim = s * inv;
        // logits in [-20, 0]: exp never overflows, no max-subtraction needed
        const float w   = __expf((sim - 1.0f) * EPS_INV);
        const float win = w * inv;

        acc_a.x += win * va.x; acc_a.y += win * va.y;
        acc_a.z += win * va.z; acc_a.w += win * va.w;
        acc_b.x += win * vb.x; acc_b.y += win * vb.y;
        acc_b.z += win * vb.z; acc_b.w += win * vb.w;
        lsum += w;   // identical in all lanes after butterfly reduce
    }

    // ---- cross-wave reduction via LDS ----
    __shared__ float lds_acc[4][CDIM];
    __shared__ float lds_l[4];
    *(float4*)&lds_acc[wave][4 * lane]              = acc_a;
    *(float4*)&lds_acc[wave][(CDIM / 2) + 4 * lane] = acc_b;
    if (lane == 0) lds_l[wave] = lsum;
    __syncthreads();

    const int t = threadIdx.x;
    const float s0 = lds_acc[0][t]       + lds_acc[1][t]
                   + lds_acc[2][t]       + lds_acc[3][t];
    const float s1 = lds_acc[0][t + 256] + lds_acc[1][t + 256]
                   + lds_acc[2][t + 256] + lds_acc[3][t + 256];
    const size_t blk = (size_t)b * chunks + chunk;
    ws_acc[blk * CDIM + t]       = s0;
    ws_acc[blk * CDIM + t + 256] = s1;
    if (t == 0)
        ws_l[blk] = lds_l[0] + lds_l[1] + lds_l[2] + lds_l[3];
}

// ---------------------------------------------------------------------------
// Pass 2: fold per-chunk partials, apply softmax denom + mass normalization.
// Grid: BATCH blocks, 256 threads. Thread t handles cols t and t+256.
// ---------------------------------------------------------------------------
__global__ __launch_bounds__(256) void uot_pass2(
    const float* __restrict__ ws_acc,
    const float* __restrict__ ws_l,
    const float* __restrict__ dustbin_param,
    float* __restrict__ out,              // [BATCH*CDIM] obs, then [BATCH] mass
    int chunks)
{
    const int b = blockIdx.x;
    const int t = threadIdx.x;
    float s0 = 0.f, s1 = 0.f, L = 0.f;
    for (int k = 0; k < chunks; ++k) {
        const size_t base = ((size_t)b * chunks + k) * CDIM;
        s0 += ws_acc[base + t];
        s1 += ws_acc[base + t + 256];
        L  += ws_l[(size_t)b * chunks + k];
    }
    const float denom = L + __expf(-dustbin_param[0] * EPS_INV);
    const float tm    = L / denom;
    const float scale = 1.0f / (denom * (tm + 1e-6f));
    out[(size_t)b * CDIM + t]       = s0 * scale;
    out[(size_t)b * CDIM + t + 256] = s1 * scale;
    if (t == 0) out[(size_t)BATCH * CDIM + b] = tm;
}

extern "C" void kernel_launch(void* const* d_in, const int* in_sizes, int n_in,
                              void* d_out, int out_size, void* d_ws, size_t ws_size,
                              hipStream_t stream) {
    const float* prompt        = (const float*)d_in[0];  // (32,1,512)
    const float* vf            = (const float*)d_in[1];  // (32,4096,512)
    // d_in[2] = dustbin_token — unused by the reference computation
    const float* dustbin_param = (const float*)d_in[3];  // (1,)
    float* out = (float*)d_out;

    // Pick chunks (blocks per batch) to fit workspace; 32 -> 1024 blocks = 4/CU
    int chunks = 32;
    while (chunks > 1) {
        size_t need = ((size_t)BATCH * chunks * CDIM + (size_t)BATCH * chunks)
                      * sizeof(float);
        if (need <= ws_size) break;
        chunks >>= 1;
    }
    float* ws_acc = (float*)d_ws;
    float* ws_l   = ws_acc + (size_t)BATCH * chunks * CDIM;

    dim3 g1(chunks, BATCH);
    uot_pass1<<<g1, 256, 0, stream>>>(prompt, vf, ws_acc, ws_l, chunks);
    uot_pass2<<<BATCH, 256, 0, stream>>>(ws_acc, ws_l, dustbin_param, out, chunks);
}

// Round 2
// 370.164 us; speedup vs baseline: 1.0119x; 1.0119x over previous
//
#include <hip/hip_runtime.h>
#include <math.h>

#define BATCH 32
#define NROWS 4096
#define CDIM  512
#define EPS_INV 10.0f   // 1/EPS_SINKHORN

// ---------------------------------------------------------------------------
// Pass 1: fused l2norm + similarity + exp-weight + weighted accumulation.
// Grid: (chunks, BATCH), block = 256 threads = 4 waves.
// Each wave processes TWO rows per iteration with half-wave ownership:
//   lanes 0-31  -> row 2*it   (each lane: 4x float4 = cols 4hl+{0,128,256,384})
//   lanes 32-63 -> row 2*it+1
// Butterfly reduce is 5 steps over 32 lanes (masks 1..16 stay within a half).
// Per-block partial acc[512] and partial sum-of-weights go to workspace.
// ---------------------------------------------------------------------------
__global__ __launch_bounds__(256) void uot_pass1(
    const float* __restrict__ prompt,     // [BATCH, CDIM]
    const float* __restrict__ vf,         // [BATCH, NROWS, CDIM]
    float* __restrict__ ws_acc,           // [BATCH*chunks, CDIM]
    float* __restrict__ ws_l,             // [BATCH*chunks]
    int chunks)
{
    const int b     = blockIdx.y;
    const int chunk = blockIdx.x;
    const int lane  = threadIdx.x & 63;
    const int wave  = threadIdx.x >> 6;
    const int half  = lane >> 5;          // 0 or 1: which row of the pair
    const int hl    = lane & 31;
    const int cb    = 4 * hl;             // column base within each 128-col band

    // ---- normalized prompt fragment: lane owns cols cb + {0,128,256,384} ----
    const float* pp = prompt + (size_t)b * CDIM;
    float4 p0 = *(const float4*)(pp + cb);
    float4 p1 = *(const float4*)(pp + 128 + cb);
    float4 p2 = *(const float4*)(pp + 256 + cb);
    float4 p3 = *(const float4*)(pp + 384 + cb);
    float ss = p0.x*p0.x + p0.y*p0.y + p0.z*p0.z + p0.w*p0.w
             + p1.x*p1.x + p1.y*p1.y + p1.z*p1.z + p1.w*p1.w
             + p2.x*p2.x + p2.y*p2.y + p2.z*p2.z + p2.w*p2.w
             + p3.x*p3.x + p3.y*p3.y + p3.z*p3.z + p3.w*p3.w;
    #pragma unroll
    for (int off = 16; off > 0; off >>= 1) ss += __shfl_xor(ss, off);
    const float pinv = 1.0f / fmaxf(sqrtf(ss), 1e-12f);
    p0.x *= pinv; p0.y *= pinv; p0.z *= pinv; p0.w *= pinv;
    p1.x *= pinv; p1.y *= pinv; p1.z *= pinv; p1.w *= pinv;
    p2.x *= pinv; p2.y *= pinv; p2.z *= pinv; p2.w *= pinv;
    p3.x *= pinv; p3.y *= pinv; p3.z *= pinv; p3.w *= pinv;

    float4 a0 = make_float4(0.f,0.f,0.f,0.f), a1 = a0, a2 = a0, a3 = a0;
    float  lsum = 0.f;   // sum of weights over THIS half's rows only

    const int rows_per_chunk = NROWS / chunks;
    const int rows_per_wave  = rows_per_chunk >> 2;
    const int pairs          = rows_per_wave >> 1;
    const int row0 = chunk * rows_per_chunk + wave * rows_per_wave;
    const float* __restrict__ base =
        vf + ((size_t)b * NROWS + row0 + half) * CDIM;

    #pragma unroll 2
    for (int it = 0; it < pairs; ++it) {
        const float* __restrict__ vrow = base + (size_t)(2 * it) * CDIM;
        const float4 v0 = *(const float4*)(vrow + cb);
        const float4 v1 = *(const float4*)(vrow + 128 + cb);
        const float4 v2 = *(const float4*)(vrow + 256 + cb);
        const float4 v3 = *(const float4*)(vrow + 384 + cb);

        float s = v0.x*p0.x + v0.y*p0.y + v0.z*p0.z + v0.w*p0.w
                + v1.x*p1.x + v1.y*p1.y + v1.z*p1.z + v1.w*p1.w
                + v2.x*p2.x + v2.y*p2.y + v2.z*p2.z + v2.w*p2.w
                + v3.x*p3.x + v3.y*p3.y + v3.z*p3.z + v3.w*p3.w;
        float q = v0.x*v0.x + v0.y*v0.y + v0.z*v0.z + v0.w*v0.w
                + v1.x*v1.x + v1.y*v1.y + v1.z*v1.z + v1.w*v1.w
                + v2.x*v2.x + v2.y*v2.y + v2.z*v2.z + v2.w*v2.w
                + v3.x*v3.x + v3.y*v3.y + v3.z*v3.z + v3.w*v3.w;

        // 5-step butterfly within each 32-lane half (masks < 32 stay in-half)
        #pragma unroll
        for (int off = 16; off > 0; off >>= 1) {
            s += __shfl_xor(s, off);
            q += __shfl_xor(q, off);
        }

        const float inv = rsqrtf(fmaxf(q, 1e-24f));
        const float sim = s * inv;
        // logits in [-20, 0]: exp never overflows, no max-subtraction needed
        const float w   = __expf((sim - 1.0f) * EPS_INV);
        const float win = w * inv;

        a0.x += win*v0.x; a0.y += win*v0.y; a0.z += win*v0.z; a0.w += win*v0.w;
        a1.x += win*v1.x; a1.y += win*v1.y; a1.z += win*v1.z; a1.w += win*v1.w;
        a2.x += win*v2.x; a2.y += win*v2.y; a2.z += win*v2.z; a2.w += win*v2.w;
        a3.x += win*v3.x; a3.y += win*v3.y; a3.z += win*v3.z; a3.w += win*v3.w;
        lsum += w;   // identical across the 32 lanes of this half
    }

    // ---- cross-group reduction via LDS: 8 groups (4 waves x 2 halves) ----
    __shared__ float lds_acc[8][CDIM];
    __shared__ float lds_l[8];
    const int g = wave * 2 + half;
    *(float4*)&lds_acc[g][cb]       = a0;
    *(float4*)&lds_acc[g][128 + cb] = a1;
    *(float4*)&lds_acc[g][256 + cb] = a2;
    *(float4*)&lds_acc[g][384 + cb] = a3;
    if (hl == 0) lds_l[g] = lsum;
    __syncthreads();

    const int t = threadIdx.x;
    float s0 = 0.f, s1 = 0.f;
    #pragma unroll
    for (int gg = 0; gg < 8; ++gg) {
        s0 += lds_acc[gg][t];
        s1 += lds_acc[gg][t + 256];
    }
    const size_t blk = (size_t)b * chunks + chunk;
    ws_acc[blk * CDIM + t]       = s0;
    ws_acc[blk * CDIM + t + 256] = s1;
    if (t == 0) {
        float L = 0.f;
        #pragma unroll
        for (int gg = 0; gg < 8; ++gg) L += lds_l[gg];
        ws_l[blk] = L;
    }
}

// ---------------------------------------------------------------------------
// Pass 2: fold per-chunk partials, apply softmax denom + mass normalization.
// Grid: BATCH blocks, 256 threads. Thread t handles cols t and t+256.
// ---------------------------------------------------------------------------
__global__ __launch_bounds__(256) void uot_pass2(
    const float* __restrict__ ws_acc,
    const float* __restrict__ ws_l,
    const float* __restrict__ dustbin_param,
    float* __restrict__ out,              // [BATCH*CDIM] obs, then [BATCH] mass
    int chunks)
{
    const int b = blockIdx.x;
    const int t = threadIdx.x;
    float s0 = 0.f, s1 = 0.f, L = 0.f;
    #pragma unroll 4
    for (int k = 0; k < chunks; ++k) {
        const size_t base = ((size_t)b * chunks + k) * CDIM;
        s0 += ws_acc[base + t];
        s1 += ws_acc[base + t + 256];
        L  += ws_l[(size_t)b * chunks + k];
    }
    const float denom = L + __expf(-dustbin_param[0] * EPS_INV);
    const float tm    = L / denom;
    const float scale = 1.0f / (denom * (tm + 1e-6f));
    out[(size_t)b * CDIM + t]       = s0 * scale;
    out[(size_t)b * CDIM + t + 256] = s1 * scale;
    if (t == 0) out[(size_t)BATCH * CDIM + b] = tm;
}

extern "C" void kernel_launch(void* const* d_in, const int* in_sizes, int n_in,
                              void* d_out, int out_size, void* d_ws, size_t ws_size,
                              hipStream_t stream) {
    const float* prompt        = (const float*)d_in[0];  // (32,1,512)
    const float* vf            = (const float*)d_in[1];  // (32,4096,512)
    // d_in[2] = dustbin_token — unused by the reference computation
    const float* dustbin_param = (const float*)d_in[3];  // (1,)
    float* out = (float*)d_out;

    // chunks (blocks per batch): 64 -> 2048 blocks = 8 blocks/CU nominal;
    // auto-shrink if workspace is small (needs BATCH*chunks*(CDIM+1) floats)
    int chunks = 64;
    while (chunks > 1) {
        size_t need = ((size_t)BATCH * chunks * CDIM + (size_t)BATCH * chunks)
                      * sizeof(float);
        if (need <= ws_size) break;
        chunks >>= 1;
    }
    float* ws_acc = (float*)d_ws;
    float* ws_l   = ws_acc + (size_t)BATCH * chunks * CDIM;

    dim3 g1(chunks, BATCH);
    uot_pass1<<<g1, 256, 0, stream>>>(prompt, vf, ws_acc, ws_l, chunks);
    uot_pass2<<<BATCH, 256, 0, stream>>>(ws_acc, ws_l, dustbin_param, out, chunks);
}